// Round 9
// baseline (320.254 us; speedup 1.0000x reference)
//
#include <hip/hip_runtime.h>
#include <stdint.h>

// y[b,o,w] = relu(bias[o] + sum_{i,kh} W[o,i,kh] * x[b,i,kh,w])
// q=i&3 split: q<2 ("rep") -> pre-sum W over tt => K=512 GEMM; q>=2 ("pos")
// keeps the gathered K=8192 GEMM, gather fused into GEMM staging from
// f1t[row][q][w][kh] bf16 (2MB, L2-resident).
// r9: finalize fused into gemm via per-tile completion counters (5
// contributors per (m,n) tile: 4 pos z-splits + 1 rep). 2 dispatches.

#define NDIM 1024
#define TK   16
#define KPOS 8192    // pos K: 512 i's * 16 kh
#define KREP 512     // rep K: 32 (nl,q) * 16 kh
#define NCOL 2048    // 64 batches * 32 width

typedef unsigned short u16;
typedef uint32_t u32;
typedef u16   u16x8  __attribute__((ext_vector_type(8)));
typedef __bf16 bf16x8 __attribute__((ext_vector_type(8)));
typedef float  f32x4  __attribute__((ext_vector_type(4)));

__device__ __forceinline__ u16 f2bf(float x) {
    union { float f; unsigned u; } v; v.f = x;
    unsigned r = 0x7FFFu + ((v.u >> 16) & 1u);   // round-to-nearest-even
    return (u16)((v.u + r) >> 16);
}

// async global->LDS, 16B/lane; LDS dest is wave-uniform base + lane*16
__device__ __forceinline__ void load_lds_16B(const u16* g, u16* l) {
    __builtin_amdgcn_global_load_lds(
        (__attribute__((address_space(1))) void*)(uintptr_t)g,
        (__attribute__((address_space(3))) void*)(unsigned)(uintptr_t)l,
        16, 0, 0);
}

// ---------------------------------------------------------------------------
// Kernel 1 (fused, grid-partitioned):
//   [0,256):      top-16 per row (wave/row, registers, exact fp32)
//   [256,2304):   zero d_out (+ block 256 zeroes the 128 tile counters)
//   [2304,6400):  conv_w pos half fp32 -> bf16 A_pos[o][k'], k'=i'*16+kh
//   [6400,7424):  W1[o][kr] = bf16(sum_tt W[o, nl*64+tt*4+q, kh]), q in {0,1}
//   [7424,7680):  f1t[row][q][w][kh^swp] = bf16(f1[row, q*512+kh*32+w]),
//                 swp = 8*((w>>2)&1)  (bank-spread half-swap for GEMM reads)
// ---------------------------------------------------------------------------
#define PREP_TOPK 256
#define PREP_ZERO 2048
#define PREP_CONV 4096
#define PREP_W1   1024
#define PREP_F1T  256

__global__ __launch_bounds__(256) void prep_kernel(const float* __restrict__ f1,
                                                   const float* __restrict__ W,
                                                   int* __restrict__ idx,
                                                   u16* __restrict__ Wb,
                                                   u16* __restrict__ W1b,
                                                   u16* __restrict__ f1t,
                                                   int* __restrict__ cnt,
                                                   float* __restrict__ out) {
    const int bid = blockIdx.x;
    const int t = threadIdx.x;
    if (bid < PREP_TOPK) {
        // ---- top-16 ----
        const int lane = t & 63;
        const int row  = bid * 4 + (t >> 6);
        float v[16];
        const float* src = f1 + row * NDIM + lane;
        #pragma unroll
        for (int j = 0; j < 16; ++j) v[j] = src[j * 64];
        for (int sel = 0; sel < TK; ++sel) {
            float best = -3.402823466e38f; int bg = 0x7fffffff;
            #pragma unroll
            for (int j = 0; j < 16; ++j)
                if (v[j] > best) { best = v[j]; bg = j * 64 + lane; }
            #pragma unroll
            for (int s = 1; s < 64; s <<= 1) {
                float ov = __shfl_xor(best, s);
                int   og = __shfl_xor(bg, s);
                if (ov > best || (ov == best && og < bg)) { best = ov; bg = og; }
            }
            if (lane == sel) idx[row * TK + sel] = bg;
            #pragma unroll
            for (int j = 0; j < 16; ++j)
                if (bg == j * 64 + lane) v[j] = -3.402823466e38f;
        }
    } else if (bid < PREP_TOPK + PREP_ZERO) {
        // ---- zero the 8MB output accumulator (+ tile counters) ----
        const int zb = bid - PREP_TOPK;
        f32x4 z = {0.f, 0.f, 0.f, 0.f};
        *(f32x4*)(out + (size_t)(zb * 256 + t) * 4) = z;
        if (zb == 0 && t < 128) cnt[t] = 0;
    } else if (bid < PREP_TOPK + PREP_ZERO + PREP_CONV) {
        // ---- conv_w pos half -> bf16: i' = nl*32+tt*2+qp, i = nl*64+tt*4+qp+2
        const int tid = (bid - PREP_TOPK - PREP_ZERO) * 256 + t;  // < 1048576
        const int o  = tid >> 10;
        const int r  = tid & 1023;
        const int kp0 = r * 8;                 // k' base (8 consecutive)
        const int ip  = r >> 1;                // i'
        const int kh0 = (r & 1) * 8;
        const int i = (ip >> 5) * 64 + ((ip >> 1) & 15) * 4 + (ip & 1) + 2;
        const float* src = W + (size_t)o * 16384 + i * 16 + kh0;
        float4 a = *(const float4*)(src);
        float4 b = *(const float4*)(src + 4);
        u16x8 ov;
        ov[0] = f2bf(a.x); ov[1] = f2bf(a.y); ov[2] = f2bf(a.z); ov[3] = f2bf(a.w);
        ov[4] = f2bf(b.x); ov[5] = f2bf(b.y); ov[6] = f2bf(b.z); ov[7] = f2bf(b.w);
        *(u16x8*)(Wb + (size_t)o * KPOS + kp0) = ov;
    } else if (bid < PREP_TOPK + PREP_ZERO + PREP_CONV + PREP_W1) {
        // ---- W1 reduction over tt (rep half) ----
        const int o = bid - PREP_TOPK - PREP_ZERO - PREP_CONV;   // 0..1023
        const float* wrow = W + (size_t)o * 16384;
        #pragma unroll
        for (int h = 0; h < 2; ++h) {
            const int kr = h * 256 + t;        // 0..511
            const int nl = kr >> 5, q = (kr >> 4) & 1, kh = kr & 15;
            const float* base = wrow + (nl * 64 + q) * 16 + kh;
            float s = 0.f;
            #pragma unroll
            for (int tt = 0; tt < 16; ++tt) s += base[tt * 64];
            W1b[o * KREP + kr] = f2bf(s);
        }
    } else {
        // ---- f1 -> f1t bf16 transpose (w-major, kh half-swapped by w>>2&1) ----
        const int gb = bid - PREP_TOPK - PREP_ZERO - PREP_CONV - PREP_W1; // 0..255
        const int unit = t >> 5;               // 0..7
        const int w = t & 31;
        const int rq = gb * 8 + unit;          // 0..2047
        const int row = rq >> 1, q = rq & 1;
        const float* src = f1 + row * NDIM + q * 512;
        const int swp = ((w >> 2) & 1) * 8;
        u16 tmp[16];
        #pragma unroll
        for (int kh = 0; kh < 16; ++kh)
            tmp[kh ^ swp] = f2bf(src[kh * 32 + w]);   // coalesced per-kh across lanes
        u16* dst = f1t + ((size_t)row * 2 + q) * 512 + w * 16;
        *(u16x8*)(dst)     = *(u16x8*)(tmp);
        *(u16x8*)(dst + 8) = *(u16x8*)(tmp + 8);
    }
}

// ---------------------------------------------------------------------------
// Kernel 2: bf16 MFMA GEMM, 128x128 tile, BK=64, B gathered inline from f1t.
//   f < 512:  pos GEMM K=8192, split-K=4 (f=m*64+u, u=(n,z); XCD = u%8)
//   f >= 512: rep GEMM K=512 (128 blocks)
// K-loop: LDS double-buffer A+B, ONE barrier per iter (r8). idx slice in LDS.
// Epilogue: scatter-atomic into zeroed out; then per-tile completion counter
// — the 5th contributor (of 4 pos z + 1 rep) applies bias+relu in place,
// reading back via atomic-fetch (coherent at the atomic serialization point).
// ---------------------------------------------------------------------------
#define BM 128
#define BN 128
#define BK 64

__global__ __launch_bounds__(256, 2) void gemm_kernel(const u16* __restrict__ Ap,
                                                      const u16* __restrict__ A1,
                                                      const u16* __restrict__ f1t,
                                                      const int* __restrict__ idx,
                                                      const float* __restrict__ bias,
                                                      int* __restrict__ cnt,
                                                      float* __restrict__ out) {
    __shared__ __align__(16) u16 As[2][BM * BK];   // 2x16KB, [row][chunk^(row&7)]
    __shared__ __align__(16) u16 Bs[2][16 * 512];  // 2x16KB, [ci][bloc][w][half]
    __shared__ int idxL[256];                       // [bl][nlz][tt]
    __shared__ int doneL;
    const int f = blockIdx.x;            // 0..639
    int m, n, kb, kiters, astride;
    const u16* Ab;
    bool isPos;
    if (f < 512) {
        m = f >> 6; const int u = f & 63; n = u & 15;
        astride = KPOS; kb = (u >> 4) * 2048; kiters = 32; Ab = Ap; isPos = true;
    } else {
        const int g = f - 512; m = g >> 4; n = g & 15;
        astride = KREP; kb = 0; kiters = 8; Ab = A1; isPos = false;
    }
    const int t    = threadIdx.x;
    const int lane = t & 63;
    const int wave = t >> 6;             // 0..3 == B-staging ci
    const int wm   = (wave >> 1) * 64;
    const int wn   = (wave & 1) * 64;
    const int quad = lane >> 4;
    const int l16  = lane & 15;
    const int sw   = l16 & 7;            // A-read chunk XOR key
    const int o0 = m * BM;
    const int n0 = n * BN;
    const int nb0 = n * 4;               // first batch of this tile
    const int nl0 = kb >> 9;             // z*4

    // preload this block's idx slice: idxL[bl*64 + nlz*16 + tt]
    if (isPos) {
        const int bl = t >> 6, nlz = (t >> 4) & 3, tt = t & 15;
        idxL[t] = idx[((nb0 + bl) * 16 + nl0 + nlz) * TK + tt];
    }

    f32x4 acc[4][4] = {};

    // A staging addresses: slot (row=32c+rA, chunk c8) holds chunk c8^(rA&7)
    const int rA = t >> 3;               // 0..31
    const int c8 = t & 7;
    const int csw = (c8 ^ (rA & 7)) * 8;
    const u16* gA = Ab + (size_t)(o0 + rA) * astride + kb + csw;
    const int ipb = kb >> 4;             // ip base

    // stage iteration `it` into buffer `nb`
    auto stage = [&](int it, int nb) {
        const int k0 = it * BK;
        u16* lA = As[nb] + t * 8;
        #pragma unroll
        for (int c = 0; c < 4; ++c)
            load_lds_16B(gA + (size_t)(c * 32) * astride + k0, lA + c * 2048);
        const int ip = ipb + it * 4 + wave;
        const int qp = ip & 1;
        int rows[4];
        if (isPos) {
            const int nlz = (ip >> 5) & 3, tt = (ip >> 1) & 15;
            #pragma unroll
            for (int bl = 0; bl < 4; ++bl)
                rows[bl] = idxL[bl * 64 + nlz * 16 + tt];
        } else {
            const int r0 = ip >> 1;
            #pragma unroll
            for (int bl = 0; bl < 4; ++bl)
                rows[bl] = (nb0 + bl) * 16 + r0;
        }
        #pragma unroll
        for (int bl = 0; bl < 4; ++bl)
            load_lds_16B(f1t + ((size_t)rows[bl] * 2 + qp) * 512 + lane * 8,
                         Bs[nb] + (wave * 4 + bl) * 512);
    };

    __syncthreads();        // idxL visible before first stage reads it
    stage(0, 0);
    __syncthreads();        // drain prologue DMA

    #pragma unroll 2
    for (int it = 0; it < kiters; ++it) {
        const int cur = it & 1;
        if (it + 1 < kiters) stage(it + 1, 1 - cur);

        #pragma unroll
        for (int ks = 0; ks < 2; ++ks) {
            bf16x8 af[4], bfr[4];
            #pragma unroll
            for (int mt = 0; mt < 4; ++mt) {
                u16x8 bits = *(const u16x8*)(As[cur] + (wm + mt * 16 + l16) * BK
                                                + (((ks * 4 + quad) ^ sw) * 8));
                af[mt] = __builtin_bit_cast(bf16x8, bits);
            }
            const int ci2 = ks * 2 + (quad >> 1);
            const int qh  = quad & 1;
            #pragma unroll
            for (int nt = 0; nt < 4; ++nt) {
                const int nn = wn + nt * 16 + l16;
                const int blocf = nn >> 5, w = nn & 31;
                u16x8 bits = *(const u16x8*)(Bs[cur] + (ci2 * 4 + blocf) * 512 + w * 16
                                                + ((qh ^ ((w >> 2) & 1)) * 8));
                bfr[nt] = __builtin_bit_cast(bf16x8, bits);
            }
            #pragma unroll
            for (int mt = 0; mt < 4; ++mt)
                #pragma unroll
                for (int nt = 0; nt < 4; ++nt)
                    acc[mt][nt] = __builtin_amdgcn_mfma_f32_16x16x32_bf16(
                        af[mt], bfr[nt], acc[mt][nt], 0, 0, 0);
        }
        __syncthreads();    // one barrier per iter: releases buf[cur] AND
                            // drains the it+1 DMAs (vmcnt(0))
    }

    // epilogue: C/D row=quad*4+reg, col=l16; atomic-accumulate at final
    // scattered position: out[(b*16+(o>>6))*2048 + (o&63)*32 + w]
    #pragma unroll
    for (int nt = 0; nt < 4; ++nt) {
        const int nn = n0 + wn + nt * 16 + l16;
        const int bb = nn >> 5, w = nn & 31;
        #pragma unroll
        for (int mt = 0; mt < 4; ++mt) {
            #pragma unroll
            for (int r = 0; r < 4; ++r) {
                const int o = o0 + wm + mt * 16 + quad * 4 + r;
                unsafeAtomicAdd(out + (size_t)(bb * 16 + (o >> 6)) * 2048
                                    + (o & 63) * 32 + w,
                                acc[mt][nt][r]);
            }
        }
    }

    // ---- fused finalize: 5th contributor to this (m,n) tile applies
    // bias+relu. Release: threadfence + syncthreads before counter bump;
    // acquire: threadfence after observing old==4. Read-back via atomic
    // fetch-add(0) -- coherent at the atomics' serialization point.
    __threadfence();
    __syncthreads();
    if (t == 0) doneL = atomicAdd(&cnt[m * 16 + n], 1);
    __syncthreads();
    if (doneL == 4) {
        __threadfence();
        #pragma unroll
        for (int j = 0; j < 2; ++j) {
            const int r = t * 2 + j;             // 0..511
            const int oi = o0 + (r >> 2);        // output channel
            const int bl = nb0 + (r & 3);        // batch
            const float bv = bias[oi];
            float* p = out + (size_t)(bl * 16 + (oi >> 6)) * 2048
                           + (oi & 63) * 32;
            #pragma unroll
            for (int w = 0; w < 32; ++w) {
                float val = unsafeAtomicAdd(p + w, 0.0f);   // coherent read
                p[w] = fmaxf(val + bv, 0.0f);
            }
        }
    }
}

// ---------------------------------------------------------------------------
extern "C" void kernel_launch(void* const* d_in, const int* in_sizes, int n_in,
                              void* d_out, int out_size, void* d_ws, size_t ws_size,
                              hipStream_t stream) {
    const float* f1   = (const float*)d_in[0];   // [1024][1024]
    const float* Wc   = (const float*)d_in[1];   // [1024][1024][16][1]
    const float* bias = (const float*)d_in[2];   // [1024]
    float* out = (float*)d_out;                  // [1024][2048]

    // workspace layout (bytes):
    //   idx:  0         (64KB)
    //   Wb:   65536     (1024*8192*2 = 16MB)
    //   W1b:  16842752  (1024*512*2  = 1MB)
    //   f1t:  17891328  (1024*2*512*2 = 2MB)
    //   cnt:  19988480  (128 ints)
    int* idx = (int*)d_ws;
    u16* Wb  = (u16*)((char*)d_ws + 65536);
    u16* W1b = (u16*)((char*)d_ws + 16842752);
    u16* f1t = (u16*)((char*)d_ws + 17891328);
    int* cnt = (int*)((char*)d_ws + 19988480);

    prep_kernel<<<PREP_TOPK + PREP_ZERO + PREP_CONV + PREP_W1 + PREP_F1T,
                  256, 0, stream>>>(f1, Wc, idx, Wb, W1b, f1t, cnt, out);
    gemm_kernel<<<512 + 128, 256, 0, stream>>>(Wb, W1b, f1t, idx, bias, cnt, out);
}

// Round 10
// 177.236 us; speedup vs baseline: 1.8069x; 1.8069x over previous
//
#include <hip/hip_runtime.h>
#include <stdint.h>

// y[b,o,w] = relu(bias[o] + sum_{i,kh} W[o,i,kh] * x[b,i,kh,w])
// q=i&3 split: q<2 ("rep") -> pre-sum W over tt => K=512 GEMM; q>=2 ("pos")
// keeps the gathered K=8192 GEMM. Gather fused into the GEMM: B fragments are
// loaded per-lane DIRECTLY from f1t[row][q][w][kh] (2MB, L2-resident) into
// registers (rows are wave-uniform); A stays LDS double-buffered, one
// barrier/iter. 3 dispatches: prep -> gemm -> finalize (r9's counter-fused
// finalize reverted: it serialized the atomic stream, 64->223us).

#define NDIM 1024
#define TK   16
#define KPOS 8192    // pos K: 512 i's * 16 kh
#define KREP 512     // rep K: 32 (nl,q) * 16 kh
#define NCOL 2048    // 64 batches * 32 width

typedef unsigned short u16;
typedef uint32_t u32;
typedef u16   u16x8  __attribute__((ext_vector_type(8)));
typedef __bf16 bf16x8 __attribute__((ext_vector_type(8)));
typedef float  f32x4  __attribute__((ext_vector_type(4)));

__device__ __forceinline__ u16 f2bf(float x) {
    union { float f; unsigned u; } v; v.f = x;
    unsigned r = 0x7FFFu + ((v.u >> 16) & 1u);   // round-to-nearest-even
    return (u16)((v.u + r) >> 16);
}

// async global->LDS, 16B/lane; LDS dest is wave-uniform base + lane*16
__device__ __forceinline__ void load_lds_16B(const u16* g, u16* l) {
    __builtin_amdgcn_global_load_lds(
        (__attribute__((address_space(1))) void*)(uintptr_t)g,
        (__attribute__((address_space(3))) void*)(unsigned)(uintptr_t)l,
        16, 0, 0);
}

// ---------------------------------------------------------------------------
// Kernel 1 (fused, grid-partitioned) — identical to r8 (known good):
//   [0,256):      top-16 per row (wave/row, registers, exact fp32)
//   [256,2304):   zero d_out
//   [2304,6400):  conv_w pos half fp32 -> bf16 A_pos[o][k'], k'=i'*16+kh
//   [6400,7424):  W1[o][kr] = bf16(sum_tt W[o, nl*64+tt*4+q, kh]), q in {0,1}
//   [7424,7680):  f1t[row][q][w][kh^swp] = bf16(f1[row, q*512+kh*32+w]),
//                 swp = 8*((w>>2)&1)  (bank/align half-swap for B reads)
// ---------------------------------------------------------------------------
#define PREP_TOPK 256
#define PREP_ZERO 2048
#define PREP_CONV 4096
#define PREP_W1   1024
#define PREP_F1T  256

__global__ __launch_bounds__(256) void prep_kernel(const float* __restrict__ f1,
                                                   const float* __restrict__ W,
                                                   int* __restrict__ idx,
                                                   u16* __restrict__ Wb,
                                                   u16* __restrict__ W1b,
                                                   u16* __restrict__ f1t,
                                                   float* __restrict__ out) {
    const int bid = blockIdx.x;
    const int t = threadIdx.x;
    if (bid < PREP_TOPK) {
        // ---- top-16 ----
        const int lane = t & 63;
        const int row  = bid * 4 + (t >> 6);
        float v[16];
        const float* src = f1 + row * NDIM + lane;
        #pragma unroll
        for (int j = 0; j < 16; ++j) v[j] = src[j * 64];
        for (int sel = 0; sel < TK; ++sel) {
            float best = -3.402823466e38f; int bg = 0x7fffffff;
            #pragma unroll
            for (int j = 0; j < 16; ++j)
                if (v[j] > best) { best = v[j]; bg = j * 64 + lane; }
            #pragma unroll
            for (int s = 1; s < 64; s <<= 1) {
                float ov = __shfl_xor(best, s);
                int   og = __shfl_xor(bg, s);
                if (ov > best || (ov == best && og < bg)) { best = ov; bg = og; }
            }
            if (lane == sel) idx[row * TK + sel] = bg;
            #pragma unroll
            for (int j = 0; j < 16; ++j)
                if (bg == j * 64 + lane) v[j] = -3.402823466e38f;
        }
    } else if (bid < PREP_TOPK + PREP_ZERO) {
        // ---- zero the 8MB output accumulator ----
        const int zb = bid - PREP_TOPK;
        f32x4 z = {0.f, 0.f, 0.f, 0.f};
        *(f32x4*)(out + (size_t)(zb * 256 + t) * 4) = z;
    } else if (bid < PREP_TOPK + PREP_ZERO + PREP_CONV) {
        // ---- conv_w pos half -> bf16: i' = nl*32+tt*2+qp, i = nl*64+tt*4+qp+2
        const int tid = (bid - PREP_TOPK - PREP_ZERO) * 256 + t;  // < 1048576
        const int o  = tid >> 10;
        const int r  = tid & 1023;
        const int kp0 = r * 8;                 // k' base (8 consecutive)
        const int ip  = r >> 1;                // i'
        const int kh0 = (r & 1) * 8;
        const int i = (ip >> 5) * 64 + ((ip >> 1) & 15) * 4 + (ip & 1) + 2;
        const float* src = W + (size_t)o * 16384 + i * 16 + kh0;
        float4 a = *(const float4*)(src);
        float4 b = *(const float4*)(src + 4);
        u16x8 ov;
        ov[0] = f2bf(a.x); ov[1] = f2bf(a.y); ov[2] = f2bf(a.z); ov[3] = f2bf(a.w);
        ov[4] = f2bf(b.x); ov[5] = f2bf(b.y); ov[6] = f2bf(b.z); ov[7] = f2bf(b.w);
        *(u16x8*)(Wb + (size_t)o * KPOS + kp0) = ov;
    } else if (bid < PREP_TOPK + PREP_ZERO + PREP_CONV + PREP_W1) {
        // ---- W1 reduction over tt (rep half) ----
        const int o = bid - PREP_TOPK - PREP_ZERO - PREP_CONV;   // 0..1023
        const float* wrow = W + (size_t)o * 16384;
        #pragma unroll
        for (int h = 0; h < 2; ++h) {
            const int kr = h * 256 + t;        // 0..511
            const int nl = kr >> 5, q = (kr >> 4) & 1, kh = kr & 15;
            const float* base = wrow + (nl * 64 + q) * 16 + kh;
            float s = 0.f;
            #pragma unroll
            for (int tt = 0; tt < 16; ++tt) s += base[tt * 64];
            W1b[o * KREP + kr] = f2bf(s);
        }
    } else {
        // ---- f1 -> f1t bf16 transpose (w-major, kh half-swapped by w>>2&1) ----
        const int gb = bid - PREP_TOPK - PREP_ZERO - PREP_CONV - PREP_W1; // 0..255
        const int unit = t >> 5;               // 0..7
        const int w = t & 31;
        const int rq = gb * 8 + unit;          // 0..2047
        const int row = rq >> 1, q = rq & 1;
        const float* src = f1 + row * NDIM + q * 512;
        const int swp = ((w >> 2) & 1) * 8;
        u16 tmp[16];
        #pragma unroll
        for (int kh = 0; kh < 16; ++kh)
            tmp[kh ^ swp] = f2bf(src[kh * 32 + w]);   // coalesced per-kh across lanes
        u16* dst = f1t + ((size_t)row * 2 + q) * 512 + w * 16;
        *(u16x8*)(dst)     = *(u16x8*)(tmp);
        *(u16x8*)(dst + 8) = *(u16x8*)(tmp + 8);
    }
}

// ---------------------------------------------------------------------------
// Kernel 2: bf16 MFMA GEMM, 128x128 tile, BK=64.
//   f < 512:  pos GEMM K=8192, split-K=4 (f=m*64+u, u=(n,z); XCD = u%8)
//   f >= 512: rep GEMM K=512 (128 blocks)
// A: LDS double-buffer via global_load_lds (row&7 chunk XOR swizzle), ONE
//    barrier/iter. B: per-lane global_load_dwordx4 DIRECT from f1t into
//    registers (rows wave-uniform via idxL broadcast; offset math identical
//    to r8's LDS read). LDS = 33KB -> 4 blocks/CU. Atomic scatter epilogue.
// ---------------------------------------------------------------------------
#define BM 128
#define BN 128
#define BK 64

__global__ __launch_bounds__(256, 4) void gemm_kernel(const u16* __restrict__ Ap,
                                                      const u16* __restrict__ A1,
                                                      const u16* __restrict__ f1t,
                                                      const int* __restrict__ idx,
                                                      float* __restrict__ out) {
    __shared__ __align__(16) u16 As[2][BM * BK];   // 2x16KB, [row][chunk^(row&7)]
    __shared__ int idxL[256];                       // [bl][nlz][tt]
    const int f = blockIdx.x;            // 0..639
    int m, n, kb, kiters, astride;
    const u16* Ab;
    bool isPos;
    if (f < 512) {
        m = f >> 6; const int u = f & 63; n = u & 15;
        astride = KPOS; kb = (u >> 4) * 2048; kiters = 32; Ab = Ap; isPos = true;
    } else {
        const int g = f - 512; m = g >> 4; n = g & 15;
        astride = KREP; kb = 0; kiters = 8; Ab = A1; isPos = false;
    }
    const int t    = threadIdx.x;
    const int lane = t & 63;
    const int wave = t >> 6;
    const int wm   = (wave >> 1) * 64;
    const int wn   = (wave & 1) * 64;
    const int quad = lane >> 4;
    const int l16  = lane & 15;
    const int sw   = l16 & 7;            // A-read chunk XOR key
    const int o0 = m * BM;
    const int n0 = n * BN;
    const int nb0 = n * 4;               // first batch of this tile
    const int nl0 = kb >> 9;             // z*4

    // preload this block's idx slice: idxL[bl*64 + nlz*16 + tt]
    if (isPos) {
        const int bl = t >> 6, nlz = (t >> 4) & 3, tt = t & 15;
        idxL[t] = idx[((nb0 + bl) * 16 + nl0 + nlz) * TK + tt];
    }

    f32x4 acc[4][4] = {};

    // A staging addresses: slot (row=32c+rA, chunk c8) holds chunk c8^(rA&7)
    const int rA = t >> 3;               // 0..31
    const int c8 = t & 7;
    const int csw = (c8 ^ (rA & 7)) * 8;
    const u16* gA = Ab + (size_t)(o0 + rA) * astride + kb + csw;
    const int ipb = kb >> 4;             // ip base

    auto stageA = [&](int it, int nb) {
        const int k0 = it * BK;
        u16* lA = As[nb] + t * 8;
        #pragma unroll
        for (int c = 0; c < 4; ++c)
            load_lds_16B(gA + (size_t)(c * 32) * astride + k0, lA + c * 2048);
    };

    __syncthreads();        // idxL visible before B reads
    stageA(0, 0);
    __syncthreads();        // drain prologue DMA

    for (int it = 0; it < kiters; ++it) {
        const int cur = it & 1;
        if (it + 1 < kiters) stageA(it + 1, 1 - cur);

        // B fragments: 8 direct 16B loads from f1t (L2-hot); rows wave-uniform
        bf16x8 bfr[2][4];
        const int qh = quad & 1;
        #pragma unroll
        for (int ks = 0; ks < 2; ++ks) {
            const int ip = ipb + it * 4 + ks * 2 + (quad >> 1);
            const int qp = ip & 1;
            #pragma unroll
            for (int nt = 0; nt < 4; ++nt) {
                const int nn = wn + nt * 16 + l16;
                const int bloc = nn >> 5, w = nn & 31;
                int row;
                if (isPos) row = idxL[bloc * 64 + ((ip >> 5) & 3) * 16 + ((ip >> 1) & 15)];
                else       row = (nb0 + bloc) * 16 + (ip >> 1);
                const u16* p = f1t + ((size_t)row * 2 + qp) * 512 + w * 16
                                   + ((qh ^ ((w >> 2) & 1)) * 8);
                bfr[ks][nt] = __builtin_bit_cast(bf16x8, *(const u16x8*)p);
            }
        }

        #pragma unroll
        for (int ks = 0; ks < 2; ++ks) {
            bf16x8 af[4];
            #pragma unroll
            for (int mt = 0; mt < 4; ++mt) {
                u16x8 bits = *(const u16x8*)(As[cur] + (wm + mt * 16 + l16) * BK
                                                + (((ks * 4 + quad) ^ sw) * 8));
                af[mt] = __builtin_bit_cast(bf16x8, bits);
            }
            #pragma unroll
            for (int mt = 0; mt < 4; ++mt)
                #pragma unroll
                for (int nt = 0; nt < 4; ++nt)
                    acc[mt][nt] = __builtin_amdgcn_mfma_f32_16x16x32_bf16(
                        af[mt], bfr[ks][nt], acc[mt][nt], 0, 0, 0);
        }
        __syncthreads();    // releases As[cur] AND drains the it+1 A-DMA
    }

    // epilogue: C/D row=quad*4+reg, col=l16; atomic-accumulate at final
    // scattered position: out[(b*16+(o>>6))*2048 + (o&63)*32 + w]
    #pragma unroll
    for (int nt = 0; nt < 4; ++nt) {
        const int nn = n0 + wn + nt * 16 + l16;
        const int bb = nn >> 5, w = nn & 31;
        #pragma unroll
        for (int mt = 0; mt < 4; ++mt) {
            #pragma unroll
            for (int r = 0; r < 4; ++r) {
                const int o = o0 + wm + mt * 16 + quad * 4 + r;
                unsafeAtomicAdd(out + (size_t)(bb * 16 + (o >> 6)) * 2048
                                    + (o & 63) * 32 + w,
                                acc[mt][nt][r]);
            }
        }
    }
}

// ---------------------------------------------------------------------------
// Kernel 3: in-place bias + relu on the accumulated output.
// ---------------------------------------------------------------------------
__global__ __launch_bounds__(256) void finalize_kernel(float* __restrict__ out,
                                                       const float* __restrict__ bias) {
    const int tid = blockIdx.x * 256 + threadIdx.x;
    const int f = tid * 4;
    const int o = ((f >> 11) & 15) * 64 + ((f & 2047) >> 5);
    const float bv = bias[o];
    float4 x = *(float4*)(out + f);
    x.x = fmaxf(x.x + bv, 0.f);
    x.y = fmaxf(x.y + bv, 0.f);
    x.z = fmaxf(x.z + bv, 0.f);
    x.w = fmaxf(x.w + bv, 0.f);
    *(float4*)(out + f) = x;
}

// ---------------------------------------------------------------------------
extern "C" void kernel_launch(void* const* d_in, const int* in_sizes, int n_in,
                              void* d_out, int out_size, void* d_ws, size_t ws_size,
                              hipStream_t stream) {
    const float* f1   = (const float*)d_in[0];   // [1024][1024]
    const float* Wc   = (const float*)d_in[1];   // [1024][1024][16][1]
    const float* bias = (const float*)d_in[2];   // [1024]
    float* out = (float*)d_out;                  // [1024][2048]

    // workspace layout (bytes):
    //   idx:  0         (64KB)
    //   Wb:   65536     (1024*8192*2 = 16MB)
    //   W1b:  16842752  (1024*512*2  = 1MB)
    //   f1t:  17891328  (1024*2*512*2 = 2MB)
    int* idx = (int*)d_ws;
    u16* Wb  = (u16*)((char*)d_ws + 65536);
    u16* W1b = (u16*)((char*)d_ws + 16842752);
    u16* f1t = (u16*)((char*)d_ws + 17891328);

    prep_kernel<<<PREP_TOPK + PREP_ZERO + PREP_CONV + PREP_W1 + PREP_F1T,
                  256, 0, stream>>>(f1, Wc, idx, Wb, W1b, f1t, out);
    gemm_kernel<<<512 + 128, 256, 0, stream>>>(Wb, W1b, f1t, idx, out);
    finalize_kernel<<<(NDIM * NCOL) / (4 * 256), 256, 0, stream>>>(out, bias);
}

// Round 11
// 172.772 us; speedup vs baseline: 1.8536x; 1.0258x over previous
//
#include <hip/hip_runtime.h>
#include <stdint.h>

// y[b,o,w] = relu(bias[o] + sum_{i,kh} W[o,i,kh] * x[b,i,kh,w])
// q=i&3 split: q<2 ("rep") -> pre-sum W over tt => K=512; q>=2 ("pos") keeps
// the gathered K=8192. Gather fused into GEMM staging from f1t[row][q][w][kh]
// (2MB, L2-resident). r11: gemm = r8 structure (local optimum) with rep
// folded into the 512 pos blocks (uniform 34-iter grid, 4 contributions per
// tile); prep W-path rewritten as a single coalesced pass (W read exactly
// once, dense) with in-register shuffle reduction for the rep half.
// 3 dispatches: prep -> gemm -> finalize.

#define NDIM 1024
#define TK   16
#define KPOS 8192    // pos K: 512 i's * 16 kh
#define KREP 512     // rep K: 32 (nl,q) * 16 kh
#define NCOL 2048    // 64 batches * 32 width

typedef unsigned short u16;
typedef uint32_t u32;
typedef u16   u16x8  __attribute__((ext_vector_type(8)));
typedef __bf16 bf16x8 __attribute__((ext_vector_type(8)));
typedef float  f32x4  __attribute__((ext_vector_type(4)));

__device__ __forceinline__ u16 f2bf(float x) {
    union { float f; unsigned u; } v; v.f = x;
    unsigned r = 0x7FFFu + ((v.u >> 16) & 1u);   // round-to-nearest-even
    return (u16)((v.u + r) >> 16);
}

// async global->LDS, 16B/lane; LDS dest is wave-uniform base + lane*16
__device__ __forceinline__ void load_lds_16B(const u16* g, u16* l) {
    __builtin_amdgcn_global_load_lds(
        (__attribute__((address_space(1))) void*)(uintptr_t)g,
        (__attribute__((address_space(3))) void*)(unsigned)(uintptr_t)l,
        16, 0, 0);
}

// ---------------------------------------------------------------------------
// Kernel 1 (fused, grid-partitioned):
//   [0,256):      top-16 per row (wave/row, registers, exact fp32)
//   [256,768):    zero d_out (512 blocks x 16KB)
//   [768,1792):   single-pass W reader: one block per o. Thread t owns floats
//                 [64t,64t+64) of row o = (nl=t>>4, tt=t&15) x q(0..3) x kh.
//                 q>=2 -> bf16 -> one coalesced 64B store to Wb[o][ip*16+kh],
//                 ip=nl*32+tt*2+(q-2). q<2 -> sum over tt via 4x shfl_xor
//                 (all-reduce within 16-lane groups) -> W1b[o][(nl*2+q)*16+kh].
//   [1792,2048):  f1t[row][q][w][kh^swp] = bf16(f1[row, q*512+kh*32+w]),
//                 swp = 8*((w>>2)&1)  (bank/align half-swap for B reads)
// ---------------------------------------------------------------------------
#define PREP_TOPK 256
#define PREP_ZERO 512
#define PREP_W    1024
#define PREP_F1T  256

__global__ __launch_bounds__(256) void prep_kernel(const float* __restrict__ f1,
                                                   const float* __restrict__ W,
                                                   int* __restrict__ idx,
                                                   u16* __restrict__ Wb,
                                                   u16* __restrict__ W1b,
                                                   u16* __restrict__ f1t,
                                                   float* __restrict__ out) {
    const int bid = blockIdx.x;
    const int t = threadIdx.x;
    if (bid < PREP_TOPK) {
        // ---- top-16 ----
        const int lane = t & 63;
        const int row  = bid * 4 + (t >> 6);
        float v[16];
        const float* src = f1 + row * NDIM + lane;
        #pragma unroll
        for (int j = 0; j < 16; ++j) v[j] = src[j * 64];
        for (int sel = 0; sel < TK; ++sel) {
            float best = -3.402823466e38f; int bg = 0x7fffffff;
            #pragma unroll
            for (int j = 0; j < 16; ++j)
                if (v[j] > best) { best = v[j]; bg = j * 64 + lane; }
            #pragma unroll
            for (int s = 1; s < 64; s <<= 1) {
                float ov = __shfl_xor(best, s);
                int   og = __shfl_xor(bg, s);
                if (ov > best || (ov == best && og < bg)) { best = ov; bg = og; }
            }
            if (lane == sel) idx[row * TK + sel] = bg;
            #pragma unroll
            for (int j = 0; j < 16; ++j)
                if (bg == j * 64 + lane) v[j] = -3.402823466e38f;
        }
    } else if (bid < PREP_TOPK + PREP_ZERO) {
        // ---- zero the 8MB output accumulator ----
        const int zb = bid - PREP_TOPK;
        f32x4 z = {0.f, 0.f, 0.f, 0.f};
        float* p = out + (size_t)zb * 4096 + t * 16;
        #pragma unroll
        for (int j = 0; j < 4; ++j) *(f32x4*)(p + j * 4) = z;
    } else if (bid < PREP_TOPK + PREP_ZERO + PREP_W) {
        // ---- single-pass W: pos bf16 + rep tt-reduction ----
        const int o = bid - PREP_TOPK - PREP_ZERO;   // 0..1023
        const int nl = t >> 4, tt = t & 15;
        const float* src = W + (size_t)o * 16384 + t * 64;
        float v[64];
        #pragma unroll
        for (int j = 0; j < 16; ++j)
            *(float4*)(v + j * 4) = *(const float4*)(src + j * 4);
        // pos half (q=2,3 -> v[32..63]): coalesced 64B store
        u16* pd = Wb + (size_t)o * KPOS + (nl * 32 + tt * 2) * 16;
        #pragma unroll
        for (int j = 0; j < 4; ++j) {
            u16x8 ov;
            #pragma unroll
            for (int e = 0; e < 8; ++e) ov[e] = f2bf(v[32 + j * 8 + e]);
            *(u16x8*)(pd + j * 8) = ov;
        }
        // rep half (q=0,1 -> v[0..31]): all-reduce over tt (16-lane groups)
        float rv[32];
        #pragma unroll
        for (int j = 0; j < 32; ++j) rv[j] = v[j];
        #pragma unroll
        for (int s = 1; s < 16; s <<= 1)
            #pragma unroll
            for (int j = 0; j < 32; ++j) rv[j] += __shfl_xor(rv[j], s);
        #pragma unroll
        for (int j4 = 0; j4 < 4; ++j4) {
            if (tt == j4) {
                u16x8 ov;
                #pragma unroll
                for (int e = 0; e < 8; ++e) ov[e] = f2bf(rv[j4 * 8 + e]);
                *(u16x8*)(W1b + o * KREP + nl * 32 + j4 * 8) = ov;
            }
        }
    } else {
        // ---- f1 -> f1t bf16 transpose (w-major, kh half-swapped by w>>2&1) ----
        const int gb = bid - PREP_TOPK - PREP_ZERO - PREP_W;   // 0..255
        const int unit = t >> 5;               // 0..7
        const int w = t & 31;
        const int rq = gb * 8 + unit;          // 0..2047
        const int row = rq >> 1, q = rq & 1;
        const float* src = f1 + row * NDIM + q * 512;
        const int swp = ((w >> 2) & 1) * 8;
        u16 tmp[16];
        #pragma unroll
        for (int kh = 0; kh < 16; ++kh)
            tmp[kh ^ swp] = f2bf(src[kh * 32 + w]);   // coalesced per-kh across lanes
        u16* dst = f1t + ((size_t)row * 2 + q) * 512 + w * 16;
        *(u16x8*)(dst)     = *(u16x8*)(tmp);
        *(u16x8*)(dst + 8) = *(u16x8*)(tmp + 8);
    }
}

// ---------------------------------------------------------------------------
// Kernel 2: bf16 MFMA GEMM, 128x128 tile, BK=64, uniform grid of 512 blocks
// (f=m*64+u, u=(n,z); XCD = u%8). Each block: 32 pos iters (its z-quarter of
// KPOS) + 2 rep iters (its z-quarter of KREP) -> 4 contributions per tile.
// A: LDS double-buffer via global_load_lds (row&7 chunk XOR swizzle), ONE
// barrier/iter (r8). B: per-wave DMA from f1t (rows via idxL broadcast for
// pos, arithmetic for rep). Atomic scatter epilogue.
// ---------------------------------------------------------------------------
#define BM 128
#define BN 128
#define BK 64
#define KITERS 34

__global__ __launch_bounds__(256, 2) void gemm_kernel(const u16* __restrict__ Ap,
                                                      const u16* __restrict__ A1,
                                                      const u16* __restrict__ f1t,
                                                      const int* __restrict__ idx,
                                                      float* __restrict__ out) {
    __shared__ __align__(16) u16 As[2][BM * BK];   // 2x16KB, [row][chunk^(row&7)]
    __shared__ __align__(16) u16 Bs[2][16 * 512];  // 2x16KB, [ci][bloc][w][half]
    __shared__ int idxL[256];                       // [bl][nlz][tt]
    const int f = blockIdx.x;            // 0..511
    const int m = f >> 6;
    const int u = f & 63;
    const int n = u & 15;
    const int z = u >> 4;
    const int t    = threadIdx.x;
    const int lane = t & 63;
    const int wave = t >> 6;             // 0..3 == B-staging ci
    const int wm   = (wave >> 1) * 64;
    const int wn   = (wave & 1) * 64;
    const int quad = lane >> 4;
    const int l16  = lane & 15;
    const int sw   = l16 & 7;            // A-read chunk XOR key
    const int o0 = m * BM;
    const int n0 = n * BN;
    const int nb0 = n * 4;               // first batch of this tile
    const int kb = z * 2048;             // pos k-offset
    const int nl0 = z * 4;

    // preload this block's idx slice: idxL[bl*64 + nlz*16 + tt]
    {
        const int bl = t >> 6, nlz = (t >> 4) & 3, tt = t & 15;
        idxL[t] = idx[((nb0 + bl) * 16 + nl0 + nlz) * TK + tt];
    }

    f32x4 acc[4][4] = {};

    // A staging addresses: slot (row=32c+rA, chunk c8) holds chunk c8^(rA&7)
    const int rA = t >> 3;               // 0..31
    const int c8 = t & 7;
    const int csw = (c8 ^ (rA & 7)) * 8;
    const u16* gApos = Ap + (size_t)(o0 + rA) * KPOS + kb + csw;
    const u16* gArep = A1 + (size_t)(o0 + rA) * KREP + z * 128 + csw;
    const int ipbp = kb >> 4;            // z*128
    const int ipbr = z * 8;

    // stage iteration `it` into buffer `nb`: it<32 = pos, it in {32,33} = rep
    auto stage = [&](int it, int nb) {
        u16* lA = As[nb] + t * 8;
        int rows[4], qp;
        if (it < 32) {
            const int k0 = it * BK;
            #pragma unroll
            for (int c = 0; c < 4; ++c)
                load_lds_16B(gApos + (size_t)(c * 32) * KPOS + k0, lA + c * 2048);
            const int ip = ipbp + it * 4 + wave;
            qp = ip & 1;
            const int nlz = (ip >> 5) & 3, tt = (ip >> 1) & 15;
            #pragma unroll
            for (int bl = 0; bl < 4; ++bl)
                rows[bl] = idxL[bl * 64 + nlz * 16 + tt];
        } else {
            const int k0 = (it - 32) * BK;
            #pragma unroll
            for (int c = 0; c < 4; ++c)
                load_lds_16B(gArep + (size_t)(c * 32) * KREP + k0, lA + c * 2048);
            const int ip = ipbr + (it - 32) * 4 + wave;
            qp = ip & 1;
            const int nlr = ip >> 1;
            #pragma unroll
            for (int bl = 0; bl < 4; ++bl)
                rows[bl] = (nb0 + bl) * 16 + nlr;
        }
        #pragma unroll
        for (int bl = 0; bl < 4; ++bl)
            load_lds_16B(f1t + ((size_t)rows[bl] * 2 + qp) * 512 + lane * 8,
                         Bs[nb] + (wave * 4 + bl) * 512);
    };

    __syncthreads();        // idxL visible before first stage reads it
    stage(0, 0);
    __syncthreads();        // drain prologue DMA

    for (int it = 0; it < KITERS; ++it) {
        const int cur = it & 1;
        if (it + 1 < KITERS) stage(it + 1, 1 - cur);

        #pragma unroll
        for (int ks = 0; ks < 2; ++ks) {
            bf16x8 af[4], bfr[4];
            #pragma unroll
            for (int mt = 0; mt < 4; ++mt) {
                u16x8 bits = *(const u16x8*)(As[cur] + (wm + mt * 16 + l16) * BK
                                                + (((ks * 4 + quad) ^ sw) * 8));
                af[mt] = __builtin_bit_cast(bf16x8, bits);
            }
            const int ci2 = ks * 2 + (quad >> 1);
            const int qh  = quad & 1;
            #pragma unroll
            for (int nt = 0; nt < 4; ++nt) {
                const int nn = wn + nt * 16 + l16;
                const int blocf = nn >> 5, w = nn & 31;
                u16x8 bits = *(const u16x8*)(Bs[cur] + (ci2 * 4 + blocf) * 512 + w * 16
                                                + ((qh ^ ((w >> 2) & 1)) * 8));
                bfr[nt] = __builtin_bit_cast(bf16x8, bits);
            }
            #pragma unroll
            for (int mt = 0; mt < 4; ++mt)
                #pragma unroll
                for (int nt = 0; nt < 4; ++nt)
                    acc[mt][nt] = __builtin_amdgcn_mfma_f32_16x16x32_bf16(
                        af[mt], bfr[nt], acc[mt][nt], 0, 0, 0);
        }
        __syncthreads();    // one barrier per iter: releases buf[cur] AND
                            // drains the it+1 DMAs (vmcnt(0))
    }

    // epilogue: C/D row=quad*4+reg, col=l16; atomic-accumulate at final
    // scattered position: out[(b*16+(o>>6))*2048 + (o&63)*32 + w]
    #pragma unroll
    for (int nt = 0; nt < 4; ++nt) {
        const int nn = n0 + wn + nt * 16 + l16;
        const int bb = nn >> 5, w = nn & 31;
        #pragma unroll
        for (int mt = 0; mt < 4; ++mt) {
            #pragma unroll
            for (int r = 0; r < 4; ++r) {
                const int o = o0 + wm + mt * 16 + quad * 4 + r;
                unsafeAtomicAdd(out + (size_t)(bb * 16 + (o >> 6)) * 2048
                                    + (o & 63) * 32 + w,
                                acc[mt][nt][r]);
            }
        }
    }
}

// ---------------------------------------------------------------------------
// Kernel 3: in-place bias + relu on the accumulated output.
// ---------------------------------------------------------------------------
__global__ __launch_bounds__(256) void finalize_kernel(float* __restrict__ out,
                                                       const float* __restrict__ bias) {
    const int tid = blockIdx.x * 256 + threadIdx.x;
    const int f = tid * 4;
    const int o = ((f >> 11) & 15) * 64 + ((f & 2047) >> 5);
    const float bv = bias[o];
    float4 x = *(float4*)(out + f);
    x.x = fmaxf(x.x + bv, 0.f);
    x.y = fmaxf(x.y + bv, 0.f);
    x.z = fmaxf(x.z + bv, 0.f);
    x.w = fmaxf(x.w + bv, 0.f);
    *(float4*)(out + f) = x;
}

// ---------------------------------------------------------------------------
extern "C" void kernel_launch(void* const* d_in, const int* in_sizes, int n_in,
                              void* d_out, int out_size, void* d_ws, size_t ws_size,
                              hipStream_t stream) {
    const float* f1   = (const float*)d_in[0];   // [1024][1024]
    const float* Wc   = (const float*)d_in[1];   // [1024][1024][16][1]
    const float* bias = (const float*)d_in[2];   // [1024]
    float* out = (float*)d_out;                  // [1024][2048]

    // workspace layout (bytes):
    //   idx:  0         (64KB)
    //   Wb:   65536     (1024*8192*2 = 16MB)
    //   W1b:  16842752  (1024*512*2  = 1MB)
    //   f1t:  17891328  (1024*2*512*2 = 2MB)
    int* idx = (int*)d_ws;
    u16* Wb  = (u16*)((char*)d_ws + 65536);
    u16* W1b = (u16*)((char*)d_ws + 16842752);
    u16* f1t = (u16*)((char*)d_ws + 17891328);

    prep_kernel<<<PREP_TOPK + PREP_ZERO + PREP_W + PREP_F1T,
                  256, 0, stream>>>(f1, Wc, idx, Wb, W1b, f1t, out);
    gemm_kernel<<<512, 256, 0, stream>>>(Wb, W1b, f1t, idx, out);
    finalize_kernel<<<(NDIM * NCOL) / (4 * 256), 256, 0, stream>>>(out, bias);
}

// Round 12
// 161.395 us; speedup vs baseline: 1.9843x; 1.0705x over previous
//
#include <hip/hip_runtime.h>
#include <stdint.h>

// y[b,o,w] = relu(bias[o] + sum_{i,kh} W[o,i,kh] * x[b,i,kh,w])
// q=i&3 split: q<2 ("rep") -> pre-sum W over tt => K=512; q>=2 ("pos") keeps
// the gathered K=8192. Gather fused into GEMM staging from f1t[row][q][w][kh]
// (2MB, L2-resident). r12: gemm = r11 (58.6us, best measured); prep W-path
// rewritten with the contiguity identity Wb[o][v] = W[o][(v>>5)*64+32+(v&31)]
// (pos half of a W row is a contiguous permutation) -> fully coalesced,
// ~20 VGPRs. 3 dispatches: prep -> gemm -> finalize.

#define NDIM 1024
#define TK   16
#define KPOS 8192    // pos K: 512 i's * 16 kh
#define KREP 512     // rep K: 32 (nl,q) * 16 kh
#define NCOL 2048    // 64 batches * 32 width

typedef unsigned short u16;
typedef uint32_t u32;
typedef u16   u16x8  __attribute__((ext_vector_type(8)));
typedef __bf16 bf16x8 __attribute__((ext_vector_type(8)));
typedef float  f32x4  __attribute__((ext_vector_type(4)));

__device__ __forceinline__ u16 f2bf(float x) {
    union { float f; unsigned u; } v; v.f = x;
    unsigned r = 0x7FFFu + ((v.u >> 16) & 1u);   // round-to-nearest-even
    return (u16)((v.u + r) >> 16);
}

// async global->LDS, 16B/lane; LDS dest is wave-uniform base + lane*16
__device__ __forceinline__ void load_lds_16B(const u16* g, u16* l) {
    __builtin_amdgcn_global_load_lds(
        (__attribute__((address_space(1))) void*)(uintptr_t)g,
        (__attribute__((address_space(3))) void*)(unsigned)(uintptr_t)l,
        16, 0, 0);
}

// ---------------------------------------------------------------------------
// Kernel 1 (fused, grid-partitioned):
//   [0,256):      top-16 per row (wave/row, registers, exact fp32)
//   [256,768):    zero d_out (512 blocks x 16KB)
//   [768,1792):   W-path, one block per o:
//                   pos: Wb[o][v] = bf16(W[o][(v>>5)*64+32+(v&31)]),
//                        v = j*2048 + t*8 (j=0..3) — both sides coalesced
//                   rep: W1b[o][kr] = bf16(sum_tt W[o][nl*1024+tt*64+e]),
//                        kr = nl*32+e  (identical to r8's mapping/order)
//   [1792,2048):  f1t[row][q][w][kh^swp] = bf16(f1[row, q*512+kh*32+w]),
//                 swp = 8*((w>>2)&1)  (bank/align half-swap for B reads)
// ---------------------------------------------------------------------------
#define PREP_TOPK 256
#define PREP_ZERO 512
#define PREP_W    1024
#define PREP_F1T  256

__global__ __launch_bounds__(256) void prep_kernel(const float* __restrict__ f1,
                                                   const float* __restrict__ W,
                                                   int* __restrict__ idx,
                                                   u16* __restrict__ Wb,
                                                   u16* __restrict__ W1b,
                                                   u16* __restrict__ f1t,
                                                   float* __restrict__ out) {
    const int bid = blockIdx.x;
    const int t = threadIdx.x;
    if (bid < PREP_TOPK) {
        // ---- top-16 ----
        const int lane = t & 63;
        const int row  = bid * 4 + (t >> 6);
        float v[16];
        const float* src = f1 + row * NDIM + lane;
        #pragma unroll
        for (int j = 0; j < 16; ++j) v[j] = src[j * 64];
        for (int sel = 0; sel < TK; ++sel) {
            float best = -3.402823466e38f; int bg = 0x7fffffff;
            #pragma unroll
            for (int j = 0; j < 16; ++j)
                if (v[j] > best) { best = v[j]; bg = j * 64 + lane; }
            #pragma unroll
            for (int s = 1; s < 64; s <<= 1) {
                float ov = __shfl_xor(best, s);
                int   og = __shfl_xor(bg, s);
                if (ov > best || (ov == best && og < bg)) { best = ov; bg = og; }
            }
            if (lane == sel) idx[row * TK + sel] = bg;
            #pragma unroll
            for (int j = 0; j < 16; ++j)
                if (bg == j * 64 + lane) v[j] = -3.402823466e38f;
        }
    } else if (bid < PREP_TOPK + PREP_ZERO) {
        // ---- zero the 8MB output accumulator ----
        const int zb = bid - PREP_TOPK;
        f32x4 z = {0.f, 0.f, 0.f, 0.f};
        float* p = out + (size_t)zb * 4096 + t * 16;
        #pragma unroll
        for (int j = 0; j < 4; ++j) *(f32x4*)(p + j * 4) = z;
    } else if (bid < PREP_TOPK + PREP_ZERO + PREP_W) {
        // ---- W-path: one block per output row o ----
        const int o = bid - PREP_TOPK - PREP_ZERO;   // 0..1023
        const float* wrow = W + (size_t)o * 16384;
        u16* wbrow = Wb + (size_t)o * KPOS;
        // pos half: contiguous permutation, coalesced read+write
        #pragma unroll
        for (int j = 0; j < 4; ++j) {
            const int v = j * 2048 + t * 8;              // pos-flat index
            const int u = ((v >> 5) << 6) + 32 + (v & 31);
            float4 a = *(const float4*)(wrow + u);
            float4 b = *(const float4*)(wrow + u + 4);
            u16x8 ov;
            ov[0] = f2bf(a.x); ov[1] = f2bf(a.y); ov[2] = f2bf(a.z); ov[3] = f2bf(a.w);
            ov[4] = f2bf(b.x); ov[5] = f2bf(b.y); ov[6] = f2bf(b.z); ov[7] = f2bf(b.w);
            *(u16x8*)(wbrow + v) = ov;
        }
        // rep half: reduce over tt (same mapping/order as r8 -> identical bits)
        #pragma unroll
        for (int h = 0; h < 2; ++h) {
            const int kr = h * 256 + t;        // 0..511
            const int nl = kr >> 5, e = kr & 31;
            const float* base = wrow + nl * 1024 + e;
            float s = 0.f;
            #pragma unroll
            for (int tt = 0; tt < 16; ++tt) s += base[tt * 64];
            W1b[o * KREP + kr] = f2bf(s);
        }
    } else {
        // ---- f1 -> f1t bf16 transpose (w-major, kh half-swapped by w>>2&1) ----
        const int gb = bid - PREP_TOPK - PREP_ZERO - PREP_W;   // 0..255
        const int unit = t >> 5;               // 0..7
        const int w = t & 31;
        const int rq = gb * 8 + unit;          // 0..2047
        const int row = rq >> 1, q = rq & 1;
        const float* src = f1 + row * NDIM + q * 512;
        const int swp = ((w >> 2) & 1) * 8;
        u16 tmp[16];
        #pragma unroll
        for (int kh = 0; kh < 16; ++kh)
            tmp[kh ^ swp] = f2bf(src[kh * 32 + w]);   // coalesced per-kh across lanes
        u16* dst = f1t + ((size_t)row * 2 + q) * 512 + w * 16;
        *(u16x8*)(dst)     = *(u16x8*)(tmp);
        *(u16x8*)(dst + 8) = *(u16x8*)(tmp + 8);
    }
}

// ---------------------------------------------------------------------------
// Kernel 2: bf16 MFMA GEMM, 128x128 tile, BK=64, uniform grid of 512 blocks
// (f=m*64+u, u=(n,z); XCD = u%8). Each block: 32 pos iters (its z-quarter of
// KPOS) + 2 rep iters (its z-quarter of KREP) -> 4 contributions per tile.
// A: LDS double-buffer via global_load_lds (row&7 chunk XOR swizzle), ONE
// barrier/iter. B: per-wave DMA from f1t (rows via idxL broadcast for pos,
// arithmetic for rep). Atomic scatter epilogue.  [r11 verbatim — 58.6us]
// ---------------------------------------------------------------------------
#define BM 128
#define BN 128
#define BK 64
#define KITERS 34

__global__ __launch_bounds__(256, 2) void gemm_kernel(const u16* __restrict__ Ap,
                                                      const u16* __restrict__ A1,
                                                      const u16* __restrict__ f1t,
                                                      const int* __restrict__ idx,
                                                      float* __restrict__ out) {
    __shared__ __align__(16) u16 As[2][BM * BK];   // 2x16KB, [row][chunk^(row&7)]
    __shared__ __align__(16) u16 Bs[2][16 * 512];  // 2x16KB, [ci][bloc][w][half]
    __shared__ int idxL[256];                       // [bl][nlz][tt]
    const int f = blockIdx.x;            // 0..511
    const int m = f >> 6;
    const int u = f & 63;
    const int n = u & 15;
    const int z = u >> 4;
    const int t    = threadIdx.x;
    const int lane = t & 63;
    const int wave = t >> 6;             // 0..3 == B-staging ci
    const int wm   = (wave >> 1) * 64;
    const int wn   = (wave & 1) * 64;
    const int quad = lane >> 4;
    const int l16  = lane & 15;
    const int sw   = l16 & 7;            // A-read chunk XOR key
    const int o0 = m * BM;
    const int n0 = n * BN;
    const int nb0 = n * 4;               // first batch of this tile
    const int kb = z * 2048;             // pos k-offset
    const int nl0 = z * 4;

    // preload this block's idx slice: idxL[bl*64 + nlz*16 + tt]
    {
        const int bl = t >> 6, nlz = (t >> 4) & 3, tt = t & 15;
        idxL[t] = idx[((nb0 + bl) * 16 + nl0 + nlz) * TK + tt];
    }

    f32x4 acc[4][4] = {};

    // A staging addresses: slot (row=32c+rA, chunk c8) holds chunk c8^(rA&7)
    const int rA = t >> 3;               // 0..31
    const int c8 = t & 7;
    const int csw = (c8 ^ (rA & 7)) * 8;
    const u16* gApos = Ap + (size_t)(o0 + rA) * KPOS + kb + csw;
    const u16* gArep = A1 + (size_t)(o0 + rA) * KREP + z * 128 + csw;
    const int ipbp = kb >> 4;            // z*128
    const int ipbr = z * 8;

    // stage iteration `it` into buffer `nb`: it<32 = pos, it in {32,33} = rep
    auto stage = [&](int it, int nb) {
        u16* lA = As[nb] + t * 8;
        int rows[4], qp;
        if (it < 32) {
            const int k0 = it * BK;
            #pragma unroll
            for (int c = 0; c < 4; ++c)
                load_lds_16B(gApos + (size_t)(c * 32) * KPOS + k0, lA + c * 2048);
            const int ip = ipbp + it * 4 + wave;
            qp = ip & 1;
            const int nlz = (ip >> 5) & 3, tt = (ip >> 1) & 15;
            #pragma unroll
            for (int bl = 0; bl < 4; ++bl)
                rows[bl] = idxL[bl * 64 + nlz * 16 + tt];
        } else {
            const int k0 = (it - 32) * BK;
            #pragma unroll
            for (int c = 0; c < 4; ++c)
                load_lds_16B(gArep + (size_t)(c * 32) * KREP + k0, lA + c * 2048);
            const int ip = ipbr + (it - 32) * 4 + wave;
            qp = ip & 1;
            const int nlr = ip >> 1;
            #pragma unroll
            for (int bl = 0; bl < 4; ++bl)
                rows[bl] = (nb0 + bl) * 16 + nlr;
        }
        #pragma unroll
        for (int bl = 0; bl < 4; ++bl)
            load_lds_16B(f1t + ((size_t)rows[bl] * 2 + qp) * 512 + lane * 8,
                         Bs[nb] + (wave * 4 + bl) * 512);
    };

    __syncthreads();        // idxL visible before first stage reads it
    stage(0, 0);
    __syncthreads();        // drain prologue DMA

    for (int it = 0; it < KITERS; ++it) {
        const int cur = it & 1;
        if (it + 1 < KITERS) stage(it + 1, 1 - cur);

        #pragma unroll
        for (int ks = 0; ks < 2; ++ks) {
            bf16x8 af[4], bfr[4];
            #pragma unroll
            for (int mt = 0; mt < 4; ++mt) {
                u16x8 bits = *(const u16x8*)(As[cur] + (wm + mt * 16 + l16) * BK
                                                + (((ks * 4 + quad) ^ sw) * 8));
                af[mt] = __builtin_bit_cast(bf16x8, bits);
            }
            const int ci2 = ks * 2 + (quad >> 1);
            const int qh  = quad & 1;
            #pragma unroll
            for (int nt = 0; nt < 4; ++nt) {
                const int nn = wn + nt * 16 + l16;
                const int blocf = nn >> 5, w = nn & 31;
                u16x8 bits = *(const u16x8*)(Bs[cur] + (ci2 * 4 + blocf) * 512 + w * 16
                                                + ((qh ^ ((w >> 2) & 1)) * 8));
                bfr[nt] = __builtin_bit_cast(bf16x8, bits);
            }
            #pragma unroll
            for (int mt = 0; mt < 4; ++mt)
                #pragma unroll
                for (int nt = 0; nt < 4; ++nt)
                    acc[mt][nt] = __builtin_amdgcn_mfma_f32_16x16x32_bf16(
                        af[mt], bfr[nt], acc[mt][nt], 0, 0, 0);
        }
        __syncthreads();    // one barrier per iter: releases buf[cur] AND
                            // drains the it+1 DMAs (vmcnt(0))
    }

    // epilogue: C/D row=quad*4+reg, col=l16; atomic-accumulate at final
    // scattered position: out[(b*16+(o>>6))*2048 + (o&63)*32 + w]
    #pragma unroll
    for (int nt = 0; nt < 4; ++nt) {
        const int nn = n0 + wn + nt * 16 + l16;
        const int bb = nn >> 5, w = nn & 31;
        #pragma unroll
        for (int mt = 0; mt < 4; ++mt) {
            #pragma unroll
            for (int r = 0; r < 4; ++r) {
                const int o = o0 + wm + mt * 16 + quad * 4 + r;
                unsafeAtomicAdd(out + (size_t)(bb * 16 + (o >> 6)) * 2048
                                    + (o & 63) * 32 + w,
                                acc[mt][nt][r]);
            }
        }
    }
}

// ---------------------------------------------------------------------------
// Kernel 3: in-place bias + relu on the accumulated output.
// ---------------------------------------------------------------------------
__global__ __launch_bounds__(256) void finalize_kernel(float* __restrict__ out,
                                                       const float* __restrict__ bias) {
    const int tid = blockIdx.x * 256 + threadIdx.x;
    const int f = tid * 4;
    const int o = ((f >> 11) & 15) * 64 + ((f & 2047) >> 5);
    const float bv = bias[o];
    float4 x = *(float4*)(out + f);
    x.x = fmaxf(x.x + bv, 0.f);
    x.y = fmaxf(x.y + bv, 0.f);
    x.z = fmaxf(x.z + bv, 0.f);
    x.w = fmaxf(x.w + bv, 0.f);
    *(float4*)(out + f) = x;
}

// ---------------------------------------------------------------------------
extern "C" void kernel_launch(void* const* d_in, const int* in_sizes, int n_in,
                              void* d_out, int out_size, void* d_ws, size_t ws_size,
                              hipStream_t stream) {
    const float* f1   = (const float*)d_in[0];   // [1024][1024]
    const float* Wc   = (const float*)d_in[1];   // [1024][1024][16][1]
    const float* bias = (const float*)d_in[2];   // [1024]
    float* out = (float*)d_out;                  // [1024][2048]

    // workspace layout (bytes):
    //   idx:  0         (64KB)
    //   Wb:   65536     (1024*8192*2 = 16MB)
    //   W1b:  16842752  (1024*512*2  = 1MB)
    //   f1t:  17891328  (1024*2*512*2 = 2MB)
    int* idx = (int*)d_ws;
    u16* Wb  = (u16*)((char*)d_ws + 65536);
    u16* W1b = (u16*)((char*)d_ws + 16842752);
    u16* f1t = (u16*)((char*)d_ws + 17891328);

    prep_kernel<<<PREP_TOPK + PREP_ZERO + PREP_W + PREP_F1T,
                  256, 0, stream>>>(f1, Wc, idx, Wb, W1b, f1t, out);
    gemm_kernel<<<512, 256, 0, stream>>>(Wb, W1b, f1t, idx, out);
    finalize_kernel<<<(NDIM * NCOL) / (4 * 256), 256, 0, stream>>>(out, bias);
}